// Round 2
// baseline (435.649 us; speedup 1.0000x reference)
//
#include <hip/hip_runtime.h>
#include <stdint.h>

// GIN forward: B=32, N=1024, D=128, L=2.
// bf16 MFMA (16x16x32) for all GEMMs, fp32 accumulate; BN stats fused into GEMM
// epilogues. adj is pre-converted to bf16 once (k0_adj) so k1's K-loop is a
// pure bf16 GEMM with register-prefetch software pipelining (BK=64).

#define BB 32
#define NN 1024
#define DD 128
#define RR 32768  // BB*NN

typedef __bf16 bf16_t;
typedef bf16_t bf16x8 __attribute__((ext_vector_type(8)));
typedef float f32x4 __attribute__((ext_vector_type(4)));

__device__ __forceinline__ unsigned short f2b(float f) {
  unsigned u = __float_as_uint(f);
  u += 0x7fff + ((u >> 16) & 1);   // round-to-nearest-even
  return (unsigned short)(u >> 16);
}

// ---------------- K0adj: adj f32 -> bf16 (streaming) ----------------
__global__ __launch_bounds__(256) void k0_adj(const float* __restrict__ adj,
                                              unsigned short* __restrict__ adj16) {
  const size_t i = ((size_t)blockIdx.x * 256 + threadIdx.x) * 16;
  alignas(16) unsigned short t[16];
#pragma unroll
  for (int u = 0; u < 4; u++) {
    float4 v = *(const float4*)(adj + i + u * 4);
    t[u * 4] = f2b(v.x); t[u * 4 + 1] = f2b(v.y);
    t[u * 4 + 2] = f2b(v.z); t[u * 4 + 3] = f2b(v.w);
  }
  *(uint4*)(adj16 + i) = *(const uint4*)&t[0];
  *(uint4*)(adj16 + i + 8) = *(const uint4*)&t[8];
}

// ---------------- K0a: x [b][n][d] f32 -> hT [b][d][n] bf16 ----------------
__global__ __launch_bounds__(256) void k0_xT(const float* __restrict__ x,
                                             unsigned short* __restrict__ hT) {
  const int b = blockIdx.x, nt = blockIdx.y, tid = threadIdx.x;
  __shared__ alignas(16) unsigned short T[128][136];
  const int r = tid >> 1, c0 = (tid & 1) * 64;
  const float* src = x + ((size_t)(b * 8 + nt) * 128 + r) * 128 + c0;
#pragma unroll
  for (int i = 0; i < 64; i += 4) {
    float4 v = *(const float4*)(src + i);
    int c = c0 + i;
    T[c][r] = f2b(v.x); T[c + 1][r] = f2b(v.y);
    T[c + 2][r] = f2b(v.z); T[c + 3][r] = f2b(v.w);
  }
  __syncthreads();
  const int d = tid >> 1, n0 = (tid & 1) * 64;
  unsigned short* dst = hT + ((size_t)b * DD + d) * NN + nt * 128 + n0;
#pragma unroll
  for (int i = 0; i < 64; i += 8)
    *(uint4*)(dst + i) = *(const uint4*)&T[d][n0 + i];
}

// ---------------- K0w: W[l][k][n] f32 -> WT[l][n][k] bf16 ----------------
__global__ __launch_bounds__(256) void k0_wT(const float* __restrict__ W1,
                                             const float* __restrict__ W2,
                                             unsigned short* __restrict__ W1T,
                                             unsigned short* __restrict__ W2T) {
  int idx = blockIdx.x * 256 + threadIdx.x;  // 0..65535
  int w = idx >> 15;
  int rem = idx & 32767;
  int l = rem >> 14;
  int n = (rem >> 7) & 127;
  int k = rem & 127;
  const float* W = w ? W2 : W1;
  unsigned short* WT = w ? W2T : W1T;
  WT[((size_t)l * 128 + n) * 128 + k] = f2b(W[((size_t)l * 128 + k) * 128 + n]);
}

// ---------------- K1: pooled[b][i][d] = sum_j adj[b][i][j] * h[b][j][d] ----
// Pure bf16 GEMM, BK=64, register-prefetch pipeline.
__global__ __launch_bounds__(256) void k1_pool(const unsigned short* __restrict__ adj16,
                                               const unsigned short* __restrict__ hT,
                                               unsigned short* __restrict__ pooled) {
  const int mt = blockIdx.x, b = blockIdx.y;
  const int tid = threadIdx.x;
  const int wave = tid >> 6, lane = tid & 63;
  const int wr = (wave >> 1) * 64, wc = (wave & 1) * 64;
  const int ln = lane & 15, q = lane >> 4;

  // stride 72 shorts = 144 B: row-to-row bank shift of 4 -> <=2-way conflict (free)
  __shared__ alignas(16) unsigned short As[128][72];
  __shared__ alignas(16) unsigned short Bs[128][72];

  const unsigned short* adjb = adj16 + ((size_t)b * NN + mt * 128) * NN;
  const unsigned short* hTb = hT + (size_t)b * DD * NN;

  f32x4 acc[4][4];
  f32x4 zero = {0.f, 0.f, 0.f, 0.f};
#pragma unroll
  for (int i = 0; i < 4; i++)
#pragma unroll
    for (int j = 0; j < 4; j++) acc[i][j] = zero;

  const int rs = tid >> 1;        // staging row 0..127
  const int c0 = (tid & 1) * 32;  // 32-short half of BK=64

  const unsigned short* pA = adjb + (size_t)rs * NN + c0;
  const unsigned short* pB = hTb + (size_t)rs * NN + c0;

  uint4 pa[4], pb[4];
#pragma unroll
  for (int u = 0; u < 4; u++) {
    pa[u] = *(const uint4*)(pA + u * 8);
    pb[u] = *(const uint4*)(pB + u * 8);
  }

  for (int k0 = 0; k0 < NN; k0 += 64) {
    __syncthreads();
#pragma unroll
    for (int u = 0; u < 4; u++) {
      *(uint4*)&As[rs][c0 + u * 8] = pa[u];
      *(uint4*)&Bs[rs][c0 + u * 8] = pb[u];
    }
    __syncthreads();
    if (k0 + 64 < NN) {  // prefetch next chunk; latency hidden behind MFMAs
      const unsigned short* qA = pA + k0 + 64;
      const unsigned short* qB = pB + k0 + 64;
#pragma unroll
      for (int u = 0; u < 4; u++) {
        pa[u] = *(const uint4*)(qA + u * 8);
        pb[u] = *(const uint4*)(qB + u * 8);
      }
    }
#pragma unroll
    for (int kk = 0; kk < 2; kk++) {
      bf16x8 af[4], bfr[4];
#pragma unroll
      for (int i = 0; i < 4; i++)
        af[i] = *(const bf16x8*)&As[wr + i * 16 + ln][kk * 32 + q * 8];
#pragma unroll
      for (int j = 0; j < 4; j++)
        bfr[j] = *(const bf16x8*)&Bs[wc + j * 16 + ln][kk * 32 + q * 8];
#pragma unroll
      for (int i = 0; i < 4; i++)
#pragma unroll
        for (int j = 0; j < 4; j++)
          acc[i][j] = __builtin_amdgcn_mfma_f32_16x16x32_bf16(af[i], bfr[j], acc[i][j], 0, 0, 0);
    }
  }

  unsigned short* outb = pooled + ((size_t)b * NN + mt * 128) * DD;
#pragma unroll
  for (int i = 0; i < 4; i++) {
    int row = wr + i * 16 + q * 4;
#pragma unroll
    for (int j = 0; j < 4; j++) {
      int col = wc + j * 16 + ln;
#pragma unroll
      for (int r = 0; r < 4; r++)
        outb[(size_t)(row + r) * DD + col] = f2b(acc[i][j][r]);
    }
  }
}

// ---------------- K2: z1 = pooled @ W1 + b1 ; col stats ----------------
__global__ __launch_bounds__(256) void k2_lin(const unsigned short* __restrict__ Ain,
                                              const unsigned short* __restrict__ WT,
                                              const float* __restrict__ bias,
                                              float* __restrict__ Z,
                                              float* __restrict__ gsum,
                                              float* __restrict__ gsq) {
  const int mt = blockIdx.x;
  const int tid = threadIdx.x;
  const int wave = tid >> 6, lane = tid & 63;
  const int wr = (wave >> 1) * 64, wc = (wave & 1) * 64;
  const int ln = lane & 15, q = lane >> 4;

  __shared__ alignas(16) unsigned short As[128][40];
  __shared__ alignas(16) unsigned short Ws[128][136];
  __shared__ float lsum[128], lsq[128];

  if (tid < 128) { lsum[tid] = 0.f; lsq[tid] = 0.f; }
#pragma unroll
  for (int p = 0; p < 8; p++) {  // stage whole WT (n-major)
    int c = tid + p * 256;
    int n = c >> 4, k8 = (c & 15) * 8;
    *(uint4*)&Ws[n][k8] = *(const uint4*)&WT[n * 128 + k8];
  }

  f32x4 acc[4][4];
  f32x4 zero = {0.f, 0.f, 0.f, 0.f};
#pragma unroll
  for (int i = 0; i < 4; i++)
#pragma unroll
    for (int j = 0; j < 4; j++) acc[i][j] = zero;

  const int rs = tid >> 1, hs = tid & 1;
  const size_t row0 = (size_t)mt * 128;

  for (int k0 = 0; k0 < 128; k0 += 32) {
    __syncthreads();
    const unsigned short* src = Ain + (row0 + rs) * 128 + k0 + hs * 16;
    *(uint4*)&As[rs][hs * 16] = *(const uint4*)src;
    *(uint4*)&As[rs][hs * 16 + 8] = *(const uint4*)(src + 8);
    __syncthreads();
    bf16x8 af[4], bfr[4];
#pragma unroll
    for (int i = 0; i < 4; i++) af[i] = *(const bf16x8*)&As[wr + i * 16 + ln][q * 8];
#pragma unroll
    for (int j = 0; j < 4; j++) bfr[j] = *(const bf16x8*)&Ws[wc + j * 16 + ln][k0 + q * 8];
#pragma unroll
    for (int i = 0; i < 4; i++)
#pragma unroll
      for (int j = 0; j < 4; j++)
        acc[i][j] = __builtin_amdgcn_mfma_f32_16x16x32_bf16(af[i], bfr[j], acc[i][j], 0, 0, 0);
  }

  float s1[4] = {0.f, 0.f, 0.f, 0.f}, s2[4] = {0.f, 0.f, 0.f, 0.f};
  float* Zb = Z + row0 * 128;
#pragma unroll
  for (int j = 0; j < 4; j++) {
    int col = wc + j * 16 + ln;
    float bc = bias[col];
#pragma unroll
    for (int i = 0; i < 4; i++) {
      int row = wr + i * 16 + q * 4;
#pragma unroll
      for (int r = 0; r < 4; r++) {
        float v = acc[i][j][r] + bc;
        Zb[(size_t)(row + r) * 128 + col] = v;
        s1[j] += v; s2[j] += v * v;
      }
    }
  }
#pragma unroll
  for (int j = 0; j < 4; j++) {
    s1[j] += __shfl_xor(s1[j], 16); s1[j] += __shfl_xor(s1[j], 32);
    s2[j] += __shfl_xor(s2[j], 16); s2[j] += __shfl_xor(s2[j], 32);
  }
  if (q == 0) {
#pragma unroll
    for (int j = 0; j < 4; j++) {
      atomicAdd(&lsum[wc + j * 16 + ln], s1[j]);
      atomicAdd(&lsq[wc + j * 16 + ln], s2[j]);
    }
  }
  __syncthreads();
  if (tid < 128) atomicAdd(&gsum[tid], lsum[tid]);
  else atomicAdd(&gsq[tid - 128], lsq[tid - 128]);
}

// ------- K3: z2 = relu(BN(z1)) @ W2 + b2 ; col stats (BN fused in A-stage) ---
__global__ __launch_bounds__(256) void k3_lin(const float* __restrict__ Zin,
                                              const float* __restrict__ gsum_in,
                                              const float* __restrict__ gsq_in,
                                              const float* __restrict__ gamma,
                                              const float* __restrict__ beta,
                                              const unsigned short* __restrict__ WT,
                                              const float* __restrict__ bias,
                                              float* __restrict__ Z,
                                              float* __restrict__ gsum,
                                              float* __restrict__ gsq) {
  const int mt = blockIdx.x;
  const int tid = threadIdx.x;
  const int wave = tid >> 6, lane = tid & 63;
  const int wr = (wave >> 1) * 64, wc = (wave & 1) * 64;
  const int ln = lane & 15, q = lane >> 4;

  __shared__ alignas(16) unsigned short As[128][40];
  __shared__ alignas(16) unsigned short Ws[128][136];
  __shared__ float lsum[128], lsq[128];
  __shared__ float nsc[128], nsh[128];

  if (tid < 128) {
    float mean = gsum_in[tid] * (1.f / 32768.f);
    float var = gsq_in[tid] * (1.f / 32768.f) - mean * mean;
    float sc = gamma[tid] * rsqrtf(var + 1e-5f);
    nsc[tid] = sc; nsh[tid] = beta[tid] - mean * sc;
    lsum[tid] = 0.f; lsq[tid] = 0.f;
  }
#pragma unroll
  for (int p = 0; p < 8; p++) {
    int c = tid + p * 256;
    int n = c >> 4, k8 = (c & 15) * 8;
    *(uint4*)&Ws[n][k8] = *(const uint4*)&WT[n * 128 + k8];
  }

  f32x4 acc[4][4];
  f32x4 zero = {0.f, 0.f, 0.f, 0.f};
#pragma unroll
  for (int i = 0; i < 4; i++)
#pragma unroll
    for (int j = 0; j < 4; j++) acc[i][j] = zero;

  const int rs = tid >> 1, hs = tid & 1;
  const size_t row0 = (size_t)mt * 128;

  for (int k0 = 0; k0 < 128; k0 += 32) {
    __syncthreads();
    {
      const float* src = Zin + (row0 + rs) * 128 + k0 + hs * 16;
      alignas(16) unsigned short t[16];
#pragma unroll
      for (int i = 0; i < 16; i += 4) {
        float4 v = *(const float4*)(src + i);
        int c = k0 + hs * 16 + i;
        t[i]     = f2b(fmaxf(fmaf(v.x, nsc[c], nsh[c]), 0.f));
        t[i + 1] = f2b(fmaxf(fmaf(v.y, nsc[c + 1], nsh[c + 1]), 0.f));
        t[i + 2] = f2b(fmaxf(fmaf(v.z, nsc[c + 2], nsh[c + 2]), 0.f));
        t[i + 3] = f2b(fmaxf(fmaf(v.w, nsc[c + 3], nsh[c + 3]), 0.f));
      }
      *(uint4*)&As[rs][hs * 16] = *(const uint4*)&t[0];
      *(uint4*)&As[rs][hs * 16 + 8] = *(const uint4*)&t[8];
    }
    __syncthreads();
    bf16x8 af[4], bfr[4];
#pragma unroll
    for (int i = 0; i < 4; i++) af[i] = *(const bf16x8*)&As[wr + i * 16 + ln][q * 8];
#pragma unroll
    for (int j = 0; j < 4; j++) bfr[j] = *(const bf16x8*)&Ws[wc + j * 16 + ln][k0 + q * 8];
#pragma unroll
    for (int i = 0; i < 4; i++)
#pragma unroll
      for (int j = 0; j < 4; j++)
        acc[i][j] = __builtin_amdgcn_mfma_f32_16x16x32_bf16(af[i], bfr[j], acc[i][j], 0, 0, 0);
  }

  float s1[4] = {0.f, 0.f, 0.f, 0.f}, s2[4] = {0.f, 0.f, 0.f, 0.f};
  float* Zb = Z + row0 * 128;
#pragma unroll
  for (int j = 0; j < 4; j++) {
    int col = wc + j * 16 + ln;
    float bc = bias[col];
#pragma unroll
    for (int i = 0; i < 4; i++) {
      int row = wr + i * 16 + q * 4;
#pragma unroll
      for (int r = 0; r < 4; r++) {
        float v = acc[i][j][r] + bc;
        Zb[(size_t)(row + r) * 128 + col] = v;
        s1[j] += v; s2[j] += v * v;
      }
    }
  }
#pragma unroll
  for (int j = 0; j < 4; j++) {
    s1[j] += __shfl_xor(s1[j], 16); s1[j] += __shfl_xor(s1[j], 32);
    s2[j] += __shfl_xor(s2[j], 16); s2[j] += __shfl_xor(s2[j], 32);
  }
  if (q == 0) {
#pragma unroll
    for (int j = 0; j < 4; j++) {
      atomicAdd(&lsum[wc + j * 16 + ln], s1[j]);
      atomicAdd(&lsq[wc + j * 16 + ln], s2[j]);
    }
  }
  __syncthreads();
  if (tid < 128) atomicAdd(&gsum[tid], lsum[tid]);
  else atomicAdd(&gsq[tid - 128], lsq[tid - 128]);
}

// -------- K4t: h = relu(BN(z2)) -> hT bf16 [b][d][n] (LDS transpose) --------
__global__ __launch_bounds__(256) void k4_bnt(const float* __restrict__ Z,
                                              const float* __restrict__ gsum,
                                              const float* __restrict__ gsq,
                                              const float* __restrict__ gamma,
                                              const float* __restrict__ beta,
                                              unsigned short* __restrict__ hT) {
  const int b = blockIdx.x, nt = blockIdx.y, tid = threadIdx.x;
  __shared__ alignas(16) unsigned short T[128][136];
  __shared__ float nsc[128], nsh[128];
  if (tid < 128) {
    float mean = gsum[tid] * (1.f / 32768.f);
    float var = gsq[tid] * (1.f / 32768.f) - mean * mean;
    float sc = gamma[tid] * rsqrtf(var + 1e-5f);
    nsc[tid] = sc; nsh[tid] = beta[tid] - mean * sc;
  }
  __syncthreads();
  const int r = tid >> 1, c0 = (tid & 1) * 64;
  const float* src = Z + ((size_t)(b * 8 + nt) * 128 + r) * 128 + c0;
#pragma unroll
  for (int i = 0; i < 64; i += 4) {
    float4 v = *(const float4*)(src + i);
    int c = c0 + i;
    T[c][r]     = f2b(fmaxf(fmaf(v.x, nsc[c], nsh[c]), 0.f));
    T[c + 1][r] = f2b(fmaxf(fmaf(v.y, nsc[c + 1], nsh[c + 1]), 0.f));
    T[c + 2][r] = f2b(fmaxf(fmaf(v.z, nsc[c + 2], nsh[c + 2]), 0.f));
    T[c + 3][r] = f2b(fmaxf(fmaf(v.w, nsc[c + 3], nsh[c + 3]), 0.f));
  }
  __syncthreads();
  const int d = tid >> 1, n0 = (tid & 1) * 64;
  unsigned short* dst = hT + ((size_t)b * DD + d) * NN + nt * 128 + n0;
#pragma unroll
  for (int i = 0; i < 64; i += 8)
    *(uint4*)(dst + i) = *(const uint4*)&T[d][n0 + i];
}

// -------- K4e: final h = relu(BN(z2)) -> d_out f32 [b][n][d] --------
__global__ __launch_bounds__(256) void k4_out(const float* __restrict__ Z,
                                              const float* __restrict__ gsum,
                                              const float* __restrict__ gsq,
                                              const float* __restrict__ gamma,
                                              const float* __restrict__ beta,
                                              float* __restrict__ out) {
  const int blk = blockIdx.x, tid = threadIdx.x;
  __shared__ float nsc[128], nsh[128];
  if (tid < 128) {
    float mean = gsum[tid] * (1.f / 32768.f);
    float var = gsq[tid] * (1.f / 32768.f) - mean * mean;
    float sc = gamma[tid] * rsqrtf(var + 1e-5f);
    nsc[tid] = sc; nsh[tid] = beta[tid] - mean * sc;
  }
  __syncthreads();
  const int r = tid >> 1, c0 = (tid & 1) * 64;
  const float* src = Z + ((size_t)blk * 128 + r) * 128 + c0;
  float* dst = out + ((size_t)blk * 128 + r) * 128 + c0;
#pragma unroll
  for (int i = 0; i < 64; i += 4) {
    float4 v = *(const float4*)(src + i);
    int c = c0 + i;
    float4 o;
    o.x = fmaxf(fmaf(v.x, nsc[c], nsh[c]), 0.f);
    o.y = fmaxf(fmaf(v.y, nsc[c + 1], nsh[c + 1]), 0.f);
    o.z = fmaxf(fmaf(v.z, nsc[c + 2], nsh[c + 2]), 0.f);
    o.w = fmaxf(fmaf(v.w, nsc[c + 3], nsh[c + 3]), 0.f);
    *(float4*)(dst + i) = o;
  }
}

extern "C" void kernel_launch(void* const* d_in, const int* in_sizes, int n_in,
                              void* d_out, int out_size, void* d_ws, size_t ws_size,
                              hipStream_t stream) {
  const float* x = (const float*)d_in[0];
  // d_in[1] = padded_nei (unused by reference)
  const float* adj = (const float*)d_in[2];
  const float* W1 = (const float*)d_in[3];
  const float* b1 = (const float*)d_in[4];
  const float* W2 = (const float*)d_in[5];
  const float* b2 = (const float*)d_in[6];
  const float* g_in = (const float*)d_in[7];
  const float* be_in = (const float*)d_in[8];
  const float* g_out = (const float*)d_in[9];
  const float* be_out = (const float*)d_in[10];
  float* out = (float*)d_out;

  char* ws = (char*)d_ws;
  unsigned short* hT = (unsigned short*)ws;                              // 8 MB
  float* z1 = (float*)(ws + 8ull * 1024 * 1024);                         // 16 MB
  float* z2 = (float*)(ws + 24ull * 1024 * 1024);                        // 16 MB
  unsigned short* pooled = (unsigned short*)(ws + 24ull * 1024 * 1024);  // aliases z2
  unsigned short* W1T = (unsigned short*)(ws + 40ull * 1024 * 1024);     // 64 KB
  unsigned short* W2T = W1T + 2 * 128 * 128;                             // 64 KB
  float* stats = (float*)(ws + 40ull * 1024 * 1024 + 256 * 1024);        // 4 x 256 f32
  unsigned short* adj16 = (unsigned short*)(ws + 48ull * 1024 * 1024);   // 64 MB

  hipMemsetAsync(stats, 0, 4 * 256 * sizeof(float), stream);

  k0_adj<<<8192, 256, 0, stream>>>(adj, adj16);
  k0_xT<<<dim3(32, 8), 256, 0, stream>>>(x, hT);
  k0_wT<<<256, 256, 0, stream>>>(W1, W2, W1T, W2T);

  for (int l = 0; l < 2; l++) {
    float* st_in = stats + (l * 2 + 0) * 256;
    float* st_out = stats + (l * 2 + 1) * 256;
    k1_pool<<<dim3(8, 32), 256, 0, stream>>>(adj16, hT, pooled);
    k2_lin<<<256, 256, 0, stream>>>(pooled, W1T + l * 16384, b1 + l * 128, z1,
                                    st_in, st_in + 128);
    k3_lin<<<256, 256, 0, stream>>>(z1, st_in, st_in + 128, g_in + l * 128,
                                    be_in + l * 128, W2T + l * 16384, b2 + l * 128,
                                    z2, st_out, st_out + 128);
    if (l == 0)
      k4_bnt<<<dim3(32, 8), 256, 0, stream>>>(z2, st_out, st_out + 128, g_out,
                                              be_out, hT);
    else
      k4_out<<<256, 256, 0, stream>>>(z2, st_out, st_out + 128, g_out + 128,
                                      be_out + 128, out);
  }
}

// Round 3
// 354.557 us; speedup vs baseline: 1.2287x; 1.2287x over previous
//
#include <hip/hip_runtime.h>
#include <stdint.h>

// GIN forward: B=32, N=1024, D=128, L=2.
// R3: fewer, fatter, better-occupied kernels.
//  - kA: pooled = adj@h (bf16 MFMA, M=64 tiles, grid 512 = 2 blocks/CU) FUSED
//        with z1 = pooled@W1+b1 (second MFMA stage from LDS) + BN stats.
//  - kB: z2 = relu(BN(z1))@W2+b2 + stats; single LDS staging pass, 1 barrier.
//  - k4: BN+ReLU epilogue (-> hT bf16 for next layer, or f32 d_out).
// All intermediates bf16 (stats on exact f32 accumulators).

#define BB 32
#define NN 1024
#define DD 128
#define RR 32768  // BB*NN

typedef __bf16 bf16_t;
typedef bf16_t bf16x8 __attribute__((ext_vector_type(8)));
typedef float f32x4 __attribute__((ext_vector_type(4)));

__device__ __forceinline__ unsigned short f2b(float f) {
  unsigned u = __float_as_uint(f);
  u += 0x7fff + ((u >> 16) & 1);  // RNE
  return (unsigned short)(u >> 16);
}
__device__ __forceinline__ float b2f(unsigned short s) {
  return __uint_as_float((unsigned)s << 16);
}

// ---------------- K0 fused: x->hT transpose (blocks 0..255) + W->WT (256..511)
__global__ __launch_bounds__(256) void k0_prep(const float* __restrict__ x,
                                               const float* __restrict__ W1,
                                               const float* __restrict__ W2,
                                               unsigned short* __restrict__ hT,
                                               unsigned short* __restrict__ W1T,
                                               unsigned short* __restrict__ W2T) {
  const int tid = threadIdx.x;
  if (blockIdx.x < 256) {
    const int b = blockIdx.x >> 3, nt = blockIdx.x & 7;
    __shared__ alignas(16) unsigned short T[128][136];
    const int r = tid >> 1, c0 = (tid & 1) * 64;
    const float* src = x + ((size_t)(b * 8 + nt) * 128 + r) * 128 + c0;
#pragma unroll
    for (int i = 0; i < 64; i += 4) {
      float4 v = *(const float4*)(src + i);
      int c = c0 + i;
      T[c][r] = f2b(v.x); T[c + 1][r] = f2b(v.y);
      T[c + 2][r] = f2b(v.z); T[c + 3][r] = f2b(v.w);
    }
    __syncthreads();
    const int d = tid >> 1, n0 = (tid & 1) * 64;
    unsigned short* dst = hT + ((size_t)b * DD + d) * NN + nt * 128 + n0;
#pragma unroll
    for (int i = 0; i < 64; i += 8)
      *(uint4*)(dst + i) = *(const uint4*)&T[d][n0 + i];
  } else {
    int idx = (blockIdx.x - 256) * 256 + tid;  // 0..65535
    int w = idx >> 15;
    int rem = idx & 32767;
    int l = rem >> 14;
    int n = (rem >> 7) & 127;
    int k = rem & 127;
    const float* W = w ? W2 : W1;
    unsigned short* WT = w ? W2T : W1T;
    WT[((size_t)l * 128 + n) * 128 + k] = f2b(W[((size_t)l * 128 + k) * 128 + n]);
  }
}

// ---------------- kA: pooled (adj@h) fused with z1 = pooled@W1 + b1 + stats --
// Block: 64 adj-rows x all 128 d. 4 waves, wave w owns cols 32w..32w+31.
__global__ __launch_bounds__(256, 2) void kA_pool_lin(
    const float* __restrict__ adj, const unsigned short* __restrict__ hT,
    const unsigned short* __restrict__ WT, const float* __restrict__ bias,
    unsigned short* __restrict__ z1b, float* __restrict__ gsum,
    float* __restrict__ gsq) {
  const int mt = blockIdx.x, b = blockIdx.y;
  const int tid = threadIdx.x;
  const int wave = tid >> 6, lane = tid & 63;
  const int wc = wave * 32;
  const int ln = lane & 15, q = lane >> 4;

  __shared__ union {
    struct {
      alignas(16) unsigned short As[64][72];   // adj tile bf16, BK=64
      alignas(16) unsigned short Bs[128][72];  // hT tile bf16
    } p1;
    alignas(16) unsigned short As2[64][136];   // pooled tile bf16 (phase 2 A)
  } sm;
  __shared__ alignas(16) unsigned short Ws[128][136];  // W1T (n-major, k-contig)

  // stage Ws once (visibility covered by first loop barrier)
#pragma unroll
  for (int p = 0; p < 8; p++) {
    int c = tid + p * 256;
    int n = c >> 4, k8 = (c & 15) * 8;
    *(uint4*)&Ws[n][k8] = *(const uint4*)&WT[n * 128 + k8];
  }

  const float* adjb = adj + ((size_t)b * NN + mt * 64) * NN;
  const unsigned short* hTb = hT + (size_t)b * DD * NN;

  f32x4 acc1[4][2];
  f32x4 zero = {0.f, 0.f, 0.f, 0.f};
#pragma unroll
  for (int i = 0; i < 4; i++) { acc1[i][0] = zero; acc1[i][1] = zero; }

  const int ar = tid >> 2, aseg = (tid & 3) * 16;  // A: 64 rows, 16-f32 segs
  const int br = tid >> 1, bh = (tid & 1) * 32;    // B: 128 rows, 32-short half
  const float* pAsrc = adjb + (size_t)ar * NN + aseg;
  const unsigned short* pBsrc = hTb + (size_t)br * NN + bh;

  float4 pa[4];
  uint4 pb[4];
#pragma unroll
  for (int u = 0; u < 4; u++) {
    pa[u] = *(const float4*)(pAsrc + u * 4);
    pb[u] = *(const uint4*)(pBsrc + u * 8);
  }

  for (int k0 = 0; k0 < NN; k0 += 64) {
    __syncthreads();
    {
      alignas(16) unsigned short t[16];
#pragma unroll
      for (int u = 0; u < 4; u++) {
        t[u * 4] = f2b(pa[u].x); t[u * 4 + 1] = f2b(pa[u].y);
        t[u * 4 + 2] = f2b(pa[u].z); t[u * 4 + 3] = f2b(pa[u].w);
      }
      *(uint4*)&sm.p1.As[ar][aseg] = *(const uint4*)&t[0];
      *(uint4*)&sm.p1.As[ar][aseg + 8] = *(const uint4*)&t[8];
#pragma unroll
      for (int u = 0; u < 4; u++) *(uint4*)&sm.p1.Bs[br][bh + u * 8] = pb[u];
    }
    __syncthreads();
    if (k0 + 64 < NN) {  // prefetch next chunk behind MFMAs
#pragma unroll
      for (int u = 0; u < 4; u++) {
        pa[u] = *(const float4*)(pAsrc + k0 + 64 + u * 4);
        pb[u] = *(const uint4*)(pBsrc + k0 + 64 + u * 8);
      }
    }
#pragma unroll
    for (int kk = 0; kk < 2; kk++) {
      bf16x8 af[4], bfr[2];
#pragma unroll
      for (int i = 0; i < 4; i++)
        af[i] = *(const bf16x8*)&sm.p1.As[i * 16 + ln][kk * 32 + q * 8];
#pragma unroll
      for (int j = 0; j < 2; j++)
        bfr[j] = *(const bf16x8*)&sm.p1.Bs[wc + j * 16 + ln][kk * 32 + q * 8];
#pragma unroll
      for (int i = 0; i < 4; i++)
#pragma unroll
        for (int j = 0; j < 2; j++)
          acc1[i][j] = __builtin_amdgcn_mfma_f32_16x16x32_bf16(af[i], bfr[j], acc1[i][j], 0, 0, 0);
    }
  }

  // pooled tile -> LDS (bf16), A-layout for phase 2
  __syncthreads();  // all phase-1 LDS reads done before overwriting union
#pragma unroll
  for (int i = 0; i < 4; i++) {
    int row = i * 16 + q * 4;
#pragma unroll
    for (int j = 0; j < 2; j++) {
      int col = wc + j * 16 + ln;
#pragma unroll
      for (int r = 0; r < 4; r++) sm.As2[row + r][col] = f2b(acc1[i][j][r]);
    }
  }
  __syncthreads();

  // phase 2: z1 = pooled @ W1  (K=128, 4 k-steps, no barriers)
  f32x4 acc2[4][2];
#pragma unroll
  for (int i = 0; i < 4; i++) { acc2[i][0] = zero; acc2[i][1] = zero; }
#pragma unroll
  for (int ks = 0; ks < 4; ks++) {
    bf16x8 af[4], bfr[2];
#pragma unroll
    for (int i = 0; i < 4; i++)
      af[i] = *(const bf16x8*)&sm.As2[i * 16 + ln][ks * 32 + q * 8];
#pragma unroll
    for (int j = 0; j < 2; j++)
      bfr[j] = *(const bf16x8*)&Ws[wc + j * 16 + ln][ks * 32 + q * 8];
#pragma unroll
    for (int i = 0; i < 4; i++)
#pragma unroll
      for (int j = 0; j < 2; j++)
        acc2[i][j] = __builtin_amdgcn_mfma_f32_16x16x32_bf16(af[i], bfr[j], acc2[i][j], 0, 0, 0);
  }

  // epilogue: +bias, write z1 bf16, column stats (cols unique per wave)
  const size_t row0 = (size_t)b * NN + mt * 64;
#pragma unroll
  for (int j = 0; j < 2; j++) {
    int col = wc + j * 16 + ln;
    float bc = bias[col];
    float s1 = 0.f, s2 = 0.f;
#pragma unroll
    for (int i = 0; i < 4; i++) {
      int row = i * 16 + q * 4;
#pragma unroll
      for (int r = 0; r < 4; r++) {
        float v = acc2[i][j][r] + bc;
        z1b[(row0 + row + r) * 128 + col] = f2b(v);
        s1 += v; s2 += v * v;
      }
    }
    s1 += __shfl_xor(s1, 16); s1 += __shfl_xor(s1, 32);
    s2 += __shfl_xor(s2, 16); s2 += __shfl_xor(s2, 32);
    if (q == 0) { atomicAdd(&gsum[col], s1); atomicAdd(&gsq[col], s2); }
  }
}

// ---------------- kB: z2 = relu(BN(z1)) @ W2 + b2 + stats ----------------
// Block: 64 rows x 128 cols; whole A-tile staged once with BN fused.
__global__ __launch_bounds__(256, 2) void kB_lin(
    const unsigned short* __restrict__ Zin, const float* __restrict__ gsum_in,
    const float* __restrict__ gsq_in, const float* __restrict__ gamma,
    const float* __restrict__ beta, const unsigned short* __restrict__ WT,
    const float* __restrict__ bias, unsigned short* __restrict__ z2b,
    float* __restrict__ gsum, float* __restrict__ gsq) {
  const int mt = blockIdx.x;
  const int tid = threadIdx.x;
  const int wave = tid >> 6, lane = tid & 63;
  const int wc = wave * 32;
  const int ln = lane & 15, q = lane >> 4;

  __shared__ alignas(16) unsigned short Az[64][136];
  __shared__ alignas(16) unsigned short Ws[128][136];
  __shared__ float nsc[128], nsh[128];

  if (tid < 128) {
    float mean = gsum_in[tid] * (1.f / 32768.f);
    float var = gsq_in[tid] * (1.f / 32768.f) - mean * mean;
    float sc = gamma[tid] * rsqrtf(var + 1e-5f);
    nsc[tid] = sc; nsh[tid] = beta[tid] - mean * sc;
  }
#pragma unroll
  for (int p = 0; p < 8; p++) {
    int c = tid + p * 256;
    int n = c >> 4, k8 = (c & 15) * 8;
    *(uint4*)&Ws[n][k8] = *(const uint4*)&WT[n * 128 + k8];
  }
  __syncthreads();  // nsc/nsh ready

  // stage A: 64x128, BN+ReLU fused. thread: row tid>>2, 32-col segment.
  const size_t row0 = (size_t)mt * 64;
  {
    const int r = tid >> 2, c0 = (tid & 3) * 32;
    const unsigned short* src = Zin + (row0 + r) * 128 + c0;
#pragma unroll
    for (int u = 0; u < 4; u++) {
      uint4 raw = *(const uint4*)(src + u * 8);
      const unsigned short* s = (const unsigned short*)&raw;
      alignas(16) unsigned short t[8];
#pragma unroll
      for (int e = 0; e < 8; e++) {
        int c = c0 + u * 8 + e;
        t[e] = f2b(fmaxf(fmaf(b2f(s[e]), nsc[c], nsh[c]), 0.f));
      }
      *(uint4*)&Az[r][c0 + u * 8] = *(const uint4*)&t[0];
    }
  }
  __syncthreads();

  f32x4 acc[4][2];
  f32x4 zero = {0.f, 0.f, 0.f, 0.f};
#pragma unroll
  for (int i = 0; i < 4; i++) { acc[i][0] = zero; acc[i][1] = zero; }
#pragma unroll
  for (int ks = 0; ks < 4; ks++) {
    bf16x8 af[4], bfr[2];
#pragma unroll
    for (int i = 0; i < 4; i++)
      af[i] = *(const bf16x8*)&Az[i * 16 + ln][ks * 32 + q * 8];
#pragma unroll
    for (int j = 0; j < 2; j++)
      bfr[j] = *(const bf16x8*)&Ws[wc + j * 16 + ln][ks * 32 + q * 8];
#pragma unroll
    for (int i = 0; i < 4; i++)
#pragma unroll
      for (int j = 0; j < 2; j++)
        acc[i][j] = __builtin_amdgcn_mfma_f32_16x16x32_bf16(af[i], bfr[j], acc[i][j], 0, 0, 0);
  }

#pragma unroll
  for (int j = 0; j < 2; j++) {
    int col = wc + j * 16 + ln;
    float bc = bias[col];
    float s1 = 0.f, s2 = 0.f;
#pragma unroll
    for (int i = 0; i < 4; i++) {
      int row = i * 16 + q * 4;
#pragma unroll
      for (int r = 0; r < 4; r++) {
        float v = acc[i][j][r] + bc;
        z2b[(row0 + row + r) * 128 + col] = f2b(v);
        s1 += v; s2 += v * v;
      }
    }
    s1 += __shfl_xor(s1, 16); s1 += __shfl_xor(s1, 32);
    s2 += __shfl_xor(s2, 16); s2 += __shfl_xor(s2, 32);
    if (q == 0) { atomicAdd(&gsum[col], s1); atomicAdd(&gsq[col], s2); }
  }
}

// -------- K4t: h = relu(BN(z2)) -> hT bf16 [b][d][n] (LDS transpose) --------
__global__ __launch_bounds__(256) void k4_bnt(const unsigned short* __restrict__ Z,
                                              const float* __restrict__ gsum,
                                              const float* __restrict__ gsq,
                                              const float* __restrict__ gamma,
                                              const float* __restrict__ beta,
                                              unsigned short* __restrict__ hT) {
  const int b = blockIdx.x, nt = blockIdx.y, tid = threadIdx.x;
  __shared__ alignas(16) unsigned short T[128][136];
  __shared__ float nsc[128], nsh[128];
  if (tid < 128) {
    float mean = gsum[tid] * (1.f / 32768.f);
    float var = gsq[tid] * (1.f / 32768.f) - mean * mean;
    float sc = gamma[tid] * rsqrtf(var + 1e-5f);
    nsc[tid] = sc; nsh[tid] = beta[tid] - mean * sc;
  }
  __syncthreads();
  const int r = tid >> 1, c0 = (tid & 1) * 64;
  const unsigned short* src = Z + ((size_t)(b * 8 + nt) * 128 + r) * 128 + c0;
#pragma unroll
  for (int u = 0; u < 8; u++) {
    uint4 raw = *(const uint4*)(src + u * 8);
    const unsigned short* s = (const unsigned short*)&raw;
#pragma unroll
    for (int e = 0; e < 8; e++) {
      int c = c0 + u * 8 + e;
      T[c][r] = f2b(fmaxf(fmaf(b2f(s[e]), nsc[c], nsh[c]), 0.f));
    }
  }
  __syncthreads();
  const int d = tid >> 1, n0 = (tid & 1) * 64;
  unsigned short* dst = hT + ((size_t)b * DD + d) * NN + nt * 128 + n0;
#pragma unroll
  for (int i = 0; i < 64; i += 8)
    *(uint4*)(dst + i) = *(const uint4*)&T[d][n0 + i];
}

// -------- K4e: final h = relu(BN(z2)) -> d_out f32 [b][n][d] --------
__global__ __launch_bounds__(256) void k4_out(const unsigned short* __restrict__ Z,
                                              const float* __restrict__ gsum,
                                              const float* __restrict__ gsq,
                                              const float* __restrict__ gamma,
                                              const float* __restrict__ beta,
                                              float* __restrict__ out) {
  const int blk = blockIdx.x, tid = threadIdx.x;
  __shared__ float nsc[128], nsh[128];
  if (tid < 128) {
    float mean = gsum[tid] * (1.f / 32768.f);
    float var = gsq[tid] * (1.f / 32768.f) - mean * mean;
    float sc = gamma[tid] * rsqrtf(var + 1e-5f);
    nsc[tid] = sc; nsh[tid] = beta[tid] - mean * sc;
  }
  __syncthreads();
  const int r = tid >> 1, c0 = (tid & 1) * 64;
  const unsigned short* src = Z + ((size_t)blk * 128 + r) * 128 + c0;
  float* dst = out + ((size_t)blk * 128 + r) * 128 + c0;
#pragma unroll
  for (int u = 0; u < 8; u++) {
    uint4 raw = *(const uint4*)(src + u * 8);
    const unsigned short* s = (const unsigned short*)&raw;
    float4 o;
    int c = c0 + u * 8;
    o.x = fmaxf(fmaf(b2f(s[0]), nsc[c], nsh[c]), 0.f);
    o.y = fmaxf(fmaf(b2f(s[1]), nsc[c + 1], nsh[c + 1]), 0.f);
    o.z = fmaxf(fmaf(b2f(s[2]), nsc[c + 2], nsh[c + 2]), 0.f);
    o.w = fmaxf(fmaf(b2f(s[3]), nsc[c + 3], nsh[c + 3]), 0.f);
    *(float4*)(dst + u * 8) = o;
    o.x = fmaxf(fmaf(b2f(s[4]), nsc[c + 4], nsh[c + 4]), 0.f);
    o.y = fmaxf(fmaf(b2f(s[5]), nsc[c + 5], nsh[c + 5]), 0.f);
    o.z = fmaxf(fmaf(b2f(s[6]), nsc[c + 6], nsh[c + 6]), 0.f);
    o.w = fmaxf(fmaf(b2f(s[7]), nsc[c + 7], nsh[c + 7]), 0.f);
    *(float4*)(dst + u * 8 + 4) = o;
  }
}

extern "C" void kernel_launch(void* const* d_in, const int* in_sizes, int n_in,
                              void* d_out, int out_size, void* d_ws, size_t ws_size,
                              hipStream_t stream) {
  const float* x = (const float*)d_in[0];
  const float* adj = (const float*)d_in[2];
  const float* W1 = (const float*)d_in[3];
  const float* b1 = (const float*)d_in[4];
  const float* W2 = (const float*)d_in[5];
  const float* b2 = (const float*)d_in[6];
  const float* g_in = (const float*)d_in[7];
  const float* be_in = (const float*)d_in[8];
  const float* g_out = (const float*)d_in[9];
  const float* be_out = (const float*)d_in[10];
  float* out = (float*)d_out;

  char* ws = (char*)d_ws;
  unsigned short* hT = (unsigned short*)ws;                           // 8 MB
  unsigned short* z1b = (unsigned short*)(ws + 8ull * 1024 * 1024);   // 8 MB
  unsigned short* z2b = (unsigned short*)(ws + 16ull * 1024 * 1024);  // 8 MB
  unsigned short* W1T = (unsigned short*)(ws + 24ull * 1024 * 1024);  // 64 KB
  unsigned short* W2T = W1T + 2 * 128 * 128;                          // 64 KB
  float* stats = (float*)(ws + 25ull * 1024 * 1024);                  // 4 x 256 f32

  hipMemsetAsync(stats, 0, 4 * 256 * sizeof(float), stream);
  k0_prep<<<512, 256, 0, stream>>>(x, W1, W2, hT, W1T, W2T);

  for (int l = 0; l < 2; l++) {
    float* st_in = stats + (l * 2 + 0) * 256;
    float* st_out = stats + (l * 2 + 1) * 256;
    kA_pool_lin<<<dim3(16, 32), 256, 0, stream>>>(adj, hT, W1T + l * 16384,
                                                  b1 + l * 128, z1b, st_in,
                                                  st_in + 128);
    kB_lin<<<512, 256, 0, stream>>>(z1b, st_in, st_in + 128, g_in + l * 128,
                                    be_in + l * 128, W2T + l * 16384,
                                    b2 + l * 128, z2b, st_out, st_out + 128);
    if (l == 0)
      k4_bnt<<<dim3(32, 8), 256, 0, stream>>>(z2b, st_out, st_out + 128, g_out,
                                              be_out, hT);
    else
      k4_out<<<256, 256, 0, stream>>>(z2b, st_out, st_out + 128, g_out + 128,
                                      be_out + 128, out);
  }
}